// Round 12
// baseline (459.844 us; speedup 1.0000x reference)
//
#include <hip/hip_runtime.h>
#include <hip/hip_bf16.h>

// FlexibleGCN forward on MI355X — Round 20:
//  * CSR build fused into ONE persistent kernel (391 blocks, 3 device-scope
//    barriers): count -> row-scan -> scatter -> finalize. Kills 3 dispatch
//    gaps + ramps; also makes true CSR cost visible in top-5 if >50us.
//    Barrier: generation-target atomic counter, __hip_atomic acq/rel,
//    391 blocks << residency capacity (5.25KB LDS, low VGPR) -> safe.
//  * histg widened to 512 columns (=NB block count now 391).
//  * MFMA dense (R19) + agg (R14 depth-16, 2048 grid-stride): unchanged.
//  * Dispatches: memset + 6 kernels (was 9).

constexpr int IN_DIM  = 128;
constexpr int HDIM    = 64;
constexpr int BSH     = 8;     // bucket shift: 256 nodes per bucket
constexpr int MAXNB   = 512;   // max buckets supported (N <= 131072)
constexpr int HISTW   = 512;   // histg row width (columns = CSR blocks)
constexpr int PADSLK  = 1792;  // per-bucket esrc slack: 256 nodes x 7 max pad

typedef short bf16x8 __attribute__((ext_vector_type(8)));
typedef float f32x4  __attribute__((ext_vector_type(4)));

__device__ __forceinline__ float bf2f(unsigned int u) {
    return __uint_as_float(u << 16);
}
__device__ __forceinline__ unsigned short f2bf_bits(float f) {
    __hip_bfloat16 b = __float2bfloat16(f);
    return *(unsigned short*)&b;
}

// ---------- persistent CSR build ----------

__device__ __forceinline__ void grid_barrier(int* cnt, int target) {
    __syncthreads();
    if (threadIdx.x == 0) {
        __threadfence();
        __hip_atomic_fetch_add(cnt, 1, __ATOMIC_ACQ_REL, __HIP_MEMORY_SCOPE_AGENT);
        while (__hip_atomic_load(cnt, __ATOMIC_ACQUIRE, __HIP_MEMORY_SCOPE_AGENT) < target)
            __builtin_amdgcn_s_sleep(1);
    }
    __syncthreads();
}

// One kernel, NB blocks (<= 512), 4 phases separated by device barriers.
__global__ __launch_bounds__(256) void csr_mega(
        const int* __restrict__ src, const int* __restrict__ dst,
        int* __restrict__ histg, int* __restrict__ btot, int* __restrict__ bar,
        int* __restrict__ staging, int2* __restrict__ rows, int* __restrict__ esrc,
        float* __restrict__ dinv, unsigned int* __restrict__ hp_rowN,
        int N, int E, int NB, int chunk) {
    __shared__ int S0[512];
    __shared__ int S1[512];
    __shared__ int S2[256];
    const int tid = threadIdx.x;
    const int bid = blockIdx.x;

    // ---- P0: count — LDS histogram of this block's edge chunk ----
    for (int i = tid; i < HISTW; i += 256) S0[i] = 0;
    __syncthreads();
    {
        int beg = bid * chunk, end = min(E, beg + chunk);
        for (int e = beg + tid; e < end; e += 256)
            atomicAdd(&S0[dst[e] >> BSH], 1);
    }
    __syncthreads();
    for (int i = tid; i < NB; i += 256) histg[(size_t)i * HISTW + bid] = S0[i];
    grid_barrier(bar, NB);

    // ---- P1: scan row bid of histg (512-wide in-block scan) ----
    {
        int i0 = tid, i1 = tid + 256;
        int v0 = (i0 < NB) ? histg[(size_t)bid * HISTW + i0] : 0;
        int v1 = (i1 < NB) ? histg[(size_t)bid * HISTW + i1] : 0;
        S0[i0] = v0; S0[i1] = v1;
        __syncthreads();
        for (int off = 1; off < 512; off <<= 1) {
            int t0 = (i0 >= off) ? S0[i0 - off] : 0;
            int t1 = (i1 >= off) ? S0[i1 - off] : 0;
            __syncthreads();
            S0[i0] += t0; S0[i1] += t1;
            __syncthreads();
        }
        if (i0 < NB) histg[(size_t)bid * HISTW + i0] = S0[i0] - v0;  // exclusive
        if (i1 < NB) histg[(size_t)bid * HISTW + i1] = S0[i1] - v1;
        if (tid == 255) btot[bid] = S0[511];
    }
    grid_barrier(bar, 2 * NB);

    // ---- P2: scatter — bucket bases + per-block offsets, staged writes ----
    {
        // inclusive scan of btot into S0
        int i0 = tid, i1 = tid + 256;
        int b0 = (i0 < NB) ? btot[i0] : 0;
        int b1 = (i1 < NB) ? btot[i1] : 0;
        S0[i0] = b0; S0[i1] = b1;
        __syncthreads();
        for (int off = 1; off < 512; off <<= 1) {
            int t0 = (i0 >= off) ? S0[i0 - off] : 0;
            int t1 = (i1 >= off) ? S0[i1 - off] : 0;
            __syncthreads();
            S0[i0] += t0; S0[i1] += t1;
            __syncthreads();
        }
        if (i0 < NB) S1[i0] = (S0[i0] - b0) + histg[(size_t)i0 * HISTW + bid];
        if (i1 < NB) S1[i1] = (S0[i1] - b1) + histg[(size_t)i1 * HISTW + bid];
        __syncthreads();
        int beg = bid * chunk, end = min(E, beg + chunk);
        for (int e = beg + tid; e < end; e += 256) {
            int s = src[e];
            int d = dst[e];
            int pos = atomicAdd(&S1[d >> BSH], 1);
            staging[pos] = (s << BSH) | (d & 255);   // src<2^17, local dst 8b
        }
    }
    grid_barrier(bar, 3 * NB);

    // ---- P3: finalize bucket bid -> rows/dinv/esrc (+zero hp row N) ----
    {
        // inclusive scan of btot into S0 (bases again)
        int i0 = tid, i1 = tid + 256;
        int b0 = (i0 < NB) ? btot[i0] : 0;
        int b1 = (i1 < NB) ? btot[i1] : 0;
        S0[i0] = b0; S0[i1] = b1;
        __syncthreads();
        for (int off = 1; off < 512; off <<= 1) {
            int t0 = (i0 >= off) ? S0[i0 - off] : 0;
            int t1 = (i1 >= off) ? S0[i1 - off] : 0;
            __syncthreads();
            S0[i0] += t0; S0[i1] += t1;
            __syncthreads();
        }
        int eend = S0[bid];
        int ebeg = eend - btot[bid];
        int ebegP = ebeg + bid * PADSLK;
        int node0 = bid << BSH;
        int nloc = min(256, N - node0);
        int* cnt = S1;
        int* sm  = S1 + 256;
        int* cur = S2;
        cnt[tid] = 0;
        __syncthreads();
        for (int e = ebeg + tid; e < eend; e += 256)
            atomicAdd(&cnt[staging[e] & 255], 1);
        __syncthreads();
        int v = cnt[tid];
        int pv = (v + 7) & ~7;
        sm[tid] = pv;
        __syncthreads();
        for (int off = 1; off < 256; off <<= 1) {
            int t = (tid >= off) ? sm[tid - off] : 0;
            __syncthreads();
            sm[tid] += t;
            __syncthreads();
        }
        int excl = sm[tid] - pv;
        cur[tid] = excl;
        __syncthreads();
        if (tid < nloc) {
            rows[node0 + tid] = make_int2(ebegP + excl, ebegP + excl + pv);
            dinv[node0 + tid] = rsqrtf((float)v + 1.0f);   // +1 self-loop
            for (int q = v; q < pv; ++q)
                esrc[ebegP + excl + q] = N;
        }
        if (bid == 0 && tid < 32) hp_rowN[tid] = 0u;       // zero hp row N
        for (int e = ebeg + tid; e < eend; e += 256) {
            int p = staging[e];
            int pos = ebegP + atomicAdd(&cur[p & 255], 1);
            esrc[pos] = p >> BSH;
        }
    }
}

// ---------- dense layers: MFMA (R19) ----------

template<int K, bool IBF16, bool SCALE, bool BIAS, bool OBF16>
__device__ __forceinline__ void mfma_gemm_body(
        const void* __restrict__ Xv, const float* __restrict__ W,
        const float* __restrict__ bias, const float* __restrict__ dinv,
        void* __restrict__ Yv, int n) {
    constexpr int STR = K + 8;                      // bf16 elems per row
    __shared__ short SMEM[2 * 64 * STR];            // At | Wt
    __shared__ float dls[64];
    short* At = SMEM;
    short* Wt = SMEM + 64 * STR;
    const int tid = threadIdx.x;
    const int node0 = blockIdx.x * 64;
    const int w = tid >> 6;
    const int lane = tid & 63;
    const int lrow = lane & 15;                     // A row / B col / D col
    const int khal = lane >> 4;                     // k-group 0..3

    // ---- stage A (bf16) ----
    if (IBF16) {
#pragma unroll
        for (int i = 0; i < K / 32; ++i) {
            int s = tid + i * 256;
            int row = s >> 3, j = s & 7;
            int grow = node0 + row;
            uint4 u = make_uint4(0, 0, 0, 0);
            if (grow < n)
                u = *(const uint4*)&((const unsigned short*)Xv)[(size_t)grow * K + j * 8];
            *(uint4*)&At[row * STR + j * 8] = u;
        }
    } else {
#pragma unroll
        for (int i = 0; i < K / 16; ++i) {
            int s = tid + i * 256;
            int row = s / (K / 4), kq = s % (K / 4);
            int grow = node0 + row;
            float4 v = make_float4(0.f, 0.f, 0.f, 0.f);
            if (grow < n)
                v = *(const float4*)&((const float*)Xv)[(size_t)grow * K + kq * 4];
            unsigned short pk[4] = {f2bf_bits(v.x), f2bf_bits(v.y),
                                    f2bf_bits(v.z), f2bf_bits(v.w)};
            *(uint2*)&At[row * STR + kq * 4] = *(uint2*)pk;
        }
    }
#pragma unroll
    for (int i = 0; i < K / 4; ++i) {
        int s = tid + i * 256;
        int k = s >> 6, c = s & 63;
        Wt[c * STR + k] = (short)f2bf_bits(W[s]);
    }
    if (SCALE && tid < 64)
        dls[tid] = (node0 + tid < n) ? dinv[node0 + tid] : 1.0f;
    __syncthreads();

    f32x4 acc[4];
#pragma unroll
    for (int ct = 0; ct < 4; ++ct)
#pragma unroll
        for (int r = 0; r < 4; ++r) acc[ct][r] = 0.f;
#pragma unroll
    for (int kt = 0; kt < K / 32; ++kt) {
        int k0 = kt * 32 + khal * 8;
        bf16x8 a = *(bf16x8*)&At[(w * 16 + lrow) * STR + k0];
#pragma unroll
        for (int ct = 0; ct < 4; ++ct) {
            bf16x8 b = *(bf16x8*)&Wt[(ct * 16 + lrow) * STR + k0];
            acc[ct] = __builtin_amdgcn_mfma_f32_16x16x32_bf16(a, b, acc[ct], 0, 0, 0);
        }
    }
    __syncthreads();

    short* Ot = SMEM;                               // [64][72] bf16
    float* Of = (float*)SMEM;                       // [64][68] f32
#pragma unroll
    for (int ct = 0; ct < 4; ++ct) {
#pragma unroll
        for (int r = 0; r < 4; ++r) {
            int row = w * 16 + khal * 4 + r;
            int col = ct * 16 + lrow;
            float v = acc[ct][r];
            if (BIAS) v += bias[col];
            if (SCALE) v *= dls[row];
            if (OBF16) Ot[row * 72 + col] = (short)f2bf_bits(v);
            else       Of[row * 68 + col] = v;
        }
    }
    __syncthreads();

    if (OBF16) {
#pragma unroll
        for (int i = 0; i < 2; ++i) {
            int s = tid + i * 256;
            int row = s >> 3, j = s & 7;
            if (node0 + row < n)
                *(uint4*)&((unsigned short*)Yv)[(size_t)(node0 + row) * 64 + j * 8] =
                    *(uint4*)&Ot[row * 72 + j * 8];
        }
    } else {
#pragma unroll
        for (int i = 0; i < 4; ++i) {
            int s = tid + i * 256;
            int row = s >> 4, q = s & 15;
            if (node0 + row < n)
                *(float4*)&((float*)Yv)[(size_t)(node0 + row) * 64 + q * 4] =
                    *(float4*)&Of[row * 68 + q * 4];
        }
    }
}

__global__ __launch_bounds__(256, 4) void mgemm1_kernel(
        const float* X, const float* W, const float* dinv, void* Y, int n) {
    mfma_gemm_body<IN_DIM, false, true, false, true>(X, W, nullptr, dinv, Y, n);
}
__global__ __launch_bounds__(256, 4) void mgemm2_kernel(
        const void* X, const float* W, const float* dinv, void* Y, int n) {
    mfma_gemm_body<HDIM, true, true, false, true>(X, W, nullptr, dinv, Y, n);
}
__global__ __launch_bounds__(256, 4) void mfc_kernel(
        const float* X, const float* W, const float* bias, void* Y, int n) {
    mfma_gemm_body<HDIM, false, false, true, false>(X, W, bias, nullptr, Y, n);
}

// ---------- aggregation: CSR-vector, 8 lanes per node (R14) ----------

template<bool OBF16>
__global__ __launch_bounds__(256) void agg_kernel(
        const uint4* __restrict__ hp4, const int* __restrict__ esrc,
        const int2* __restrict__ rows, const float* __restrict__ dinv,
        const float* __restrict__ bias, void* __restrict__ out, int n) {
    const int lane = threadIdx.x & 63;
    const int j = lane & 7;
    const int step = gridDim.x * 32;
    for (int idx = blockIdx.x * 32 + (threadIdx.x >> 6) * 8 + (lane >> 3);
         idx < n; idx += step) {
        const int node = idx;
        const int2 be = rows[node];

        float acc[8];
        {   // self-loop: own row
            uint4 u = hp4[(size_t)node * 8 + j];
            acc[0] = bf2f(u.x & 0xffff); acc[1] = bf2f(u.x >> 16);
            acc[2] = bf2f(u.y & 0xffff); acc[3] = bf2f(u.y >> 16);
            acc[4] = bf2f(u.z & 0xffff); acc[5] = bf2f(u.z >> 16);
            acc[6] = bf2f(u.w & 0xffff); acc[7] = bf2f(u.w >> 16);
        }
        int k = be.x;
        for (; k + 16 <= be.y; k += 16) {       // depth-16 batches
            int s[16];
#pragma unroll
            for (int i = 0; i < 16; ++i)
                s[i] = __builtin_nontemporal_load(&esrc[k + i]);
            uint4 u[16];
#pragma unroll
            for (int i = 0; i < 16; ++i)
                u[i] = hp4[(size_t)s[i] * 8 + j];
#pragma unroll
            for (int i = 0; i < 16; ++i) {
                acc[0] += bf2f(u[i].x & 0xffff); acc[1] += bf2f(u[i].x >> 16);
                acc[2] += bf2f(u[i].y & 0xffff); acc[3] += bf2f(u[i].y >> 16);
                acc[4] += bf2f(u[i].z & 0xffff); acc[5] += bf2f(u[i].z >> 16);
                acc[6] += bf2f(u[i].w & 0xffff); acc[7] += bf2f(u[i].w >> 16);
            }
        }
        if (k < be.y) {                          // padded => exactly 8 left
            int s[8];
#pragma unroll
            for (int i = 0; i < 8; ++i)
                s[i] = __builtin_nontemporal_load(&esrc[k + i]);
            uint4 u[8];
#pragma unroll
            for (int i = 0; i < 8; ++i)
                u[i] = hp4[(size_t)s[i] * 8 + j];
#pragma unroll
            for (int i = 0; i < 8; ++i) {
                acc[0] += bf2f(u[i].x & 0xffff); acc[1] += bf2f(u[i].x >> 16);
                acc[2] += bf2f(u[i].y & 0xffff); acc[3] += bf2f(u[i].y >> 16);
                acc[4] += bf2f(u[i].z & 0xffff); acc[5] += bf2f(u[i].z >> 16);
                acc[6] += bf2f(u[i].w & 0xffff); acc[7] += bf2f(u[i].w >> 16);
            }
        }
        const float d = dinv[node];
        float o[8];
#pragma unroll
        for (int t = 0; t < 8; ++t)
            o[t] = fmaxf(fmaf(d, acc[t], bias[8 * j + t]), 0.f);

        if (OBF16) {
            uint4 pk;
            pk.x = (unsigned)f2bf_bits(o[0]) | ((unsigned)f2bf_bits(o[1]) << 16);
            pk.y = (unsigned)f2bf_bits(o[2]) | ((unsigned)f2bf_bits(o[3]) << 16);
            pk.z = (unsigned)f2bf_bits(o[4]) | ((unsigned)f2bf_bits(o[5]) << 16);
            pk.w = (unsigned)f2bf_bits(o[6]) | ((unsigned)f2bf_bits(o[7]) << 16);
            ((uint4*)out)[(size_t)node * 8 + j] = pk;
        } else {
            ((float4*)out)[(size_t)node * 16 + 2 * j]     = make_float4(o[0], o[1], o[2], o[3]);
            ((float4*)out)[(size_t)node * 16 + 2 * j + 1] = make_float4(o[4], o[5], o[6], o[7]);
        }
    }
}

extern "C" void kernel_launch(void* const* d_in, const int* in_sizes, int n_in,
                              void* d_out, int out_size, void* d_ws, size_t ws_size,
                              hipStream_t stream) {
    const float* x   = (const float*)d_in[0];
    const float* W1  = (const float*)d_in[1];
    const float* b1  = (const float*)d_in[2];
    const float* W2  = (const float*)d_in[3];
    const float* b2  = (const float*)d_in[4];
    const float* Wfc = (const float*)d_in[5];
    const float* bfc = (const float*)d_in[6];
    const int*  eidx = (const int*)d_in[7];

    const int N = in_sizes[0] / IN_DIM;     // 100000
    const int E = in_sizes[7] / 2;          // 1600000
    const int* src = eidx;
    const int* dst = eidx + E;

    const int NB    = (N + 255) >> BSH;     // 391 buckets = CSR grid
    const int chunk = (E + NB - 1) / NB;    // edges per CSR block
    const int EP    = E + NB * PADSLK;      // padded esrc capacity

    // ws layout (ints, regions 16B-aligned):
    // rows[N] int2 | dinv[N] | histg[NB*512] | btot[512] | bar[16]
    //   | esrc[EP] | hp[(N+1) rows x 128B] (row N zero) | h1[N rows x 128B]
    // staging int[E] aliases hp (dead before mgemm1 writes hp).
    int* p = (int*)d_ws;
    int2* rows = (int2*)p;           p += (size_t)2 * N + 2;
    float* dinv = (float*)p;         p += (size_t)((N + 3) & ~3);
    int* histg = p;                  p += (size_t)NB * HISTW;
    int* btot = p;                   p += 512;
    int* bar = p;                    p += 16;
    int* esrc = p;                   p += (size_t)((EP + 3) & ~3);
    unsigned short* hp = (unsigned short*)p;   p += (size_t)(N + 1) * 32;
    unsigned short* h1 = (unsigned short*)p;   p += (size_t)N * 32;
    int* staging = (int*)hp;                   // E ints < (N+1)*32 ints
    unsigned int* hp_rowN = (unsigned int*)(hp + (size_t)N * 64);

    float* emb    = (float*)d_out;
    float* logits = emb + (size_t)N * HDIM;

    const int mB = (N + 63) / 64;           // 1563 MFMA tiles
    const int aBlocks = 2048;               // 256 CU x 8 blocks, grid-stride

    // ---- CSR build: one persistent kernel (barrier counter zeroed first) ----
    hipMemsetAsync(bar, 0, 16 * sizeof(int), stream);
    csr_mega<<<NB, 256, 0, stream>>>(src, dst, histg, btot, bar, staging,
                                     rows, esrc, dinv, hp_rowN, N, E, NB, chunk);

    // ---- layer 1 ----
    mgemm1_kernel<<<mB, 256, 0, stream>>>(x, W1, dinv, hp, N);
    agg_kernel<true><<<aBlocks, 256, 0, stream>>>(
        (const uint4*)hp, esrc, rows, dinv, b1, h1, N);

    // ---- layer 2 ----
    mgemm2_kernel<<<mB, 256, 0, stream>>>(h1, W2, dinv, hp, N);
    agg_kernel<false><<<aBlocks, 256, 0, stream>>>(
        (const uint4*)hp, esrc, rows, dinv, b2, emb, N);

    // ---- FC head ----
    mfc_kernel<<<mB, 256, 0, stream>>>(emb, Wfc, bfc, logits, N);
}

// Round 14
// 292.640 us; speedup vs baseline: 1.5714x; 1.5714x over previous
//
#include <hip/hip_runtime.h>
#include <hip/hip_bf16.h>

// FlexibleGCN forward on MI355X — Round 22 (= R21 resubmit; container died):
//  * Dense MFMA tiles 64 -> 128 rows (4 waves x 32 rows): half the blocks,
//    half the W-stage/convert work, same MFMA count.
//  * binA_count fused into gemm1's dispatch (blocks [0,256) count, rest
//    gemm tiles). gemm1 runs BEFORE dinv exists -> writes unscaled hp;
//    binB_finalize rescales hp rows in place (R18-proven, absmax ok).
//  * staging un-aliased from hp (gemm1 writes hp before scatter runs).
//  * CSR scan/scatter/finalize + agg: R14/R19-identical. 8 dispatches.

constexpr int IN_DIM  = 128;
constexpr int HDIM    = 64;
constexpr int NBLK_A  = 256;   // count/scatter blocks (histg width)
constexpr int BSH     = 8;     // bucket shift: 256 nodes per bucket
constexpr int MAXNB   = 512;   // max buckets supported (N <= 131072)
constexpr int PADSLK  = 1792;  // per-bucket esrc slack: 256 nodes x 7 max pad

typedef short bf16x8 __attribute__((ext_vector_type(8)));
typedef float f32x4  __attribute__((ext_vector_type(4)));

__device__ __forceinline__ float bf2f(unsigned int u) {
    return __uint_as_float(u << 16);
}
__device__ __forceinline__ unsigned short f2bf_bits(float f) {
    __hip_bfloat16 b = __float2bfloat16(f);
    return *(unsigned short*)&b;
}

// ---------- CSR helpers (R14) ----------

__device__ __forceinline__ void bucket_scan(const int* __restrict__ btot,
                                            int* bb, int NB) {
    int tid = threadIdx.x;
    for (int i = tid; i < MAXNB; i += 256) bb[i] = (i < NB) ? btot[i] : 0;
    __syncthreads();
    for (int off = 1; off < MAXNB; off <<= 1) {
        int i0 = tid, i1 = tid + 256;
        int t0 = (i0 >= off) ? bb[i0 - off] : 0;
        int t1 = (i1 >= off) ? bb[i1 - off] : 0;
        __syncthreads();
        bb[i0] += t0;
        bb[i1] += t1;
        __syncthreads();
    }
}

__global__ void binA_scanblocks(int* __restrict__ histg, int* __restrict__ btot) {
    __shared__ int sm[NBLK_A];
    int tid = threadIdx.x;
    int v = histg[blockIdx.x * NBLK_A + tid];
    sm[tid] = v;
    __syncthreads();
    for (int off = 1; off < NBLK_A; off <<= 1) {
        int t = (tid >= off) ? sm[tid - off] : 0;
        __syncthreads();
        sm[tid] += t;
        __syncthreads();
    }
    histg[blockIdx.x * NBLK_A + tid] = sm[tid] - v;   // exclusive
    if (tid == NBLK_A - 1) btot[blockIdx.x] = sm[tid];
}

__global__ void binA_scatter(const int* __restrict__ src, const int* __restrict__ dst,
                             const int* __restrict__ histg, const int* __restrict__ btot,
                             int* __restrict__ staging, int E, int NB, int chunk) {
    __shared__ int bb[MAXNB];
    __shared__ int cur[MAXNB];
    bucket_scan(btot, bb, NB);
    for (int i = threadIdx.x; i < NB; i += 256)
        cur[i] = (bb[i] - btot[i]) + histg[i * NBLK_A + blockIdx.x];
    __syncthreads();
    int beg = blockIdx.x * chunk;
    int end = min(E, beg + chunk);
    for (int e = beg + threadIdx.x; e < end; e += 256) {
        int s = src[e];
        int d = dst[e];
        int pos = atomicAdd(&cur[d >> BSH], 1);
        staging[pos] = (s << BSH) | (d & 255);    // src<2^17, local dst 8 bits
    }
}

// finalize + in-place hp rescale by dinv (gemm1 wrote unscaled bf16 rows).
__global__ void binB_finalize(const int* __restrict__ staging, const int* __restrict__ btot,
                              int2* __restrict__ rows, int* __restrict__ esrc,
                              float* __restrict__ dinv, uint4* __restrict__ hp4,
                              int N, int NB) {
    __shared__ int bb[MAXNB];
    __shared__ int cnt[256], sm[256], cur[256];
    __shared__ float dls[256];
    int tid = threadIdx.x;
    int b = blockIdx.x;
    bucket_scan(btot, bb, NB);
    int node0 = b << BSH;
    int nloc = min(256, N - node0);
    int eend = bb[b];
    int ebeg = eend - btot[b];
    int ebegP = ebeg + b * PADSLK;            // padded bucket base
    cnt[tid] = 0;
    dls[tid] = 1.0f;
    __syncthreads();
    for (int e = ebeg + tid; e < eend; e += 256)
        atomicAdd(&cnt[staging[e] & 255], 1);
    __syncthreads();
    int v = cnt[tid];
    int pv = (v + 7) & ~7;                    // padded count
    sm[tid] = pv;
    __syncthreads();
    for (int off = 1; off < 256; off <<= 1) {
        int t = (tid >= off) ? sm[tid - off] : 0;
        __syncthreads();
        sm[tid] += t;
        __syncthreads();
    }
    int excl = sm[tid] - pv;                  // padded exclusive offset
    cur[tid] = excl;
    __syncthreads();
    if (tid < nloc) {
        float d = rsqrtf((float)v + 1.0f);    // +1 self-loop
        rows[node0 + tid] = make_int2(ebegP + excl, ebegP + excl + pv);
        dinv[node0 + tid] = d;
        dls[tid] = d;
        for (int q = v; q < pv; ++q)          // fill pad slots -> zero row
            esrc[ebegP + excl + q] = N;
    }
    if (b == 0 && tid < 8) hp4[(size_t)N * 8 + tid] = make_uint4(0, 0, 0, 0);
    for (int e = ebeg + tid; e < eend; e += 256) {
        int p = staging[e];
        int pos = ebegP + atomicAdd(&cur[p & 255], 1);
        esrc[pos] = p >> BSH;
    }
    __syncthreads();
    // rescale hp rows of this bucket by dinv
    int m = nloc * 8;                         // uint4 elems in bucket
    uint4* hpq = hp4 + (size_t)node0 * 8;
    for (int q = tid; q < m; q += 256) {
        float dd = dls[q >> 3];
        uint4 u = hpq[q];
        unsigned int r[4];
        const unsigned int* up = &u.x;
#pragma unroll
        for (int c = 0; c < 4; ++c) {
            float lo = bf2f(up[c] & 0xffff) * dd;
            float hi = bf2f(up[c] >> 16) * dd;
            r[c] = (unsigned)f2bf_bits(lo) | ((unsigned)f2bf_bits(hi) << 16);
        }
        hpq[q] = make_uint4(r[0], r[1], r[2], r[3]);
    }
}

// ---------- dense layers: MFMA, 128-row tiles ----------
// Block: 256 thr = 4 waves; tile 128 rows x 64 cols; wave w owns rows
// w*32..w*32+31 (2 row-frags). K steps of 32 (mfma_f32_16x16x32_bf16).
// At[128][K+8] bf16, Wt[64][K+8] bf16 (transposed), output LDS-bounced.
template<int K, bool OBF16>
constexpr int smem_bytes() {
    int stg = (128 + 64) * (K + 8) * 2;
    int out = OBF16 ? 128 * 72 * 2 : 128 * 68 * 4;
    return stg > out ? stg : out;
}

template<int K, bool IBF16, bool SCALE, bool BIAS, bool OBF16>
__device__ __forceinline__ void mfma_gemm_body(
        char* __restrict__ SMEMC, const void* __restrict__ Xv,
        const float* __restrict__ W, const float* __restrict__ bias,
        const float* __restrict__ dinv, void* __restrict__ Yv, int n, int bid) {
    constexpr int STR = K + 8;
    __shared__ float dls[128];
    short* At = (short*)SMEMC;                      // [128][STR]
    short* Wt = At + 128 * STR;                     // [64][STR]
    const int tid = threadIdx.x;
    const int node0 = bid * 128;
    const int w = tid >> 6;
    const int lane = tid & 63;
    const int lrow = lane & 15;                     // A row / B col / D col
    const int khal = lane >> 4;                     // k-group 0..3

    // ---- stage A (bf16) ----
    if (IBF16) {
#pragma unroll
        for (int i = 0; i < K / 16; ++i) {          // 128*(K/8) uint4
            int s = tid + i * 256;
            int row = s / (K / 8), j = s % (K / 8);
            int grow = node0 + row;
            uint4 u = make_uint4(0, 0, 0, 0);
            if (grow < n)
                u = *(const uint4*)&((const unsigned short*)Xv)[(size_t)grow * K + j * 8];
            *(uint4*)&At[row * STR + j * 8] = u;
        }
    } else {
#pragma unroll
        for (int i = 0; i < K / 8; ++i) {           // 128*(K/4) float4
            int s = tid + i * 256;
            int row = s / (K / 4), kq = s % (K / 4);
            int grow = node0 + row;
            float4 v = make_float4(0.f, 0.f, 0.f, 0.f);
            if (grow < n)
                v = *(const float4*)&((const float*)Xv)[(size_t)grow * K + kq * 4];
            unsigned short pk[4] = {f2bf_bits(v.x), f2bf_bits(v.y),
                                    f2bf_bits(v.z), f2bf_bits(v.w)};
            *(uint2*)&At[row * STR + kq * 4] = *(uint2*)pk;
        }
    }
    // ---- stage Wt (transposed, bf16) ----
#pragma unroll
    for (int i = 0; i < K / 4; ++i) {
        int s = tid + i * 256;                      // K*64 scalars
        int k = s >> 6, c = s & 63;
        Wt[c * STR + k] = (short)f2bf_bits(W[s]);
    }
    if (SCALE && tid < 128)
        dls[tid] = (node0 + tid < n) ? dinv[node0 + tid] : 1.0f;
    __syncthreads();

    // ---- MFMA ----
    f32x4 acc[2][4];
#pragma unroll
    for (int rt = 0; rt < 2; ++rt)
#pragma unroll
        for (int ct = 0; ct < 4; ++ct)
#pragma unroll
            for (int r = 0; r < 4; ++r) acc[rt][ct][r] = 0.f;
#pragma unroll
    for (int kt = 0; kt < K / 32; ++kt) {
        int k0 = kt * 32 + khal * 8;
        bf16x8 b[4];
#pragma unroll
        for (int ct = 0; ct < 4; ++ct)
            b[ct] = *(bf16x8*)&Wt[(ct * 16 + lrow) * STR + k0];
#pragma unroll
        for (int rt = 0; rt < 2; ++rt) {
            bf16x8 a = *(bf16x8*)&At[(w * 32 + rt * 16 + lrow) * STR + k0];
#pragma unroll
            for (int ct = 0; ct < 4; ++ct)
                acc[rt][ct] = __builtin_amdgcn_mfma_f32_16x16x32_bf16(a, b[ct], acc[rt][ct], 0, 0, 0);
        }
    }
    __syncthreads();                                // At/Wt reads done

    // ---- epilogue -> LDS stage (aliases SMEM) ----
    short* Ot = (short*)SMEMC;                      // [128][72] bf16
    float* Of = (float*)SMEMC;                      // [128][68] f32
#pragma unroll
    for (int rt = 0; rt < 2; ++rt) {
#pragma unroll
        for (int ct = 0; ct < 4; ++ct) {
#pragma unroll
            for (int r = 0; r < 4; ++r) {
                int row = w * 32 + rt * 16 + khal * 4 + r;
                int col = ct * 16 + lrow;
                float v = acc[rt][ct][r];
                if (BIAS) v += bias[col];
                if (SCALE) v *= dls[row];
                if (OBF16) Ot[row * 72 + col] = (short)f2bf_bits(v);
                else       Of[row * 68 + col] = v;
            }
        }
    }
    __syncthreads();

    // ---- coalesced global write ----
    if (OBF16) {
#pragma unroll
        for (int i = 0; i < 4; ++i) {
            int s = tid + i * 256;                  // 1024 uint4
            int row = s >> 3, j = s & 7;
            if (node0 + row < n)
                *(uint4*)&((unsigned short*)Yv)[(size_t)(node0 + row) * 64 + j * 8] =
                    *(uint4*)&Ot[row * 72 + j * 8];
        }
    } else {
#pragma unroll
        for (int i = 0; i < 8; ++i) {
            int s = tid + i * 256;                  // 2048 float4
            int row = s >> 4, q = s & 15;
            if (node0 + row < n)
                *(float4*)&((float*)Yv)[(size_t)(node0 + row) * 64 + q * 4] =
                    *(float4*)&Of[row * 68 + q * 4];
        }
    }
}

// D1: binA_count on blocks [0, NBLK_A); gemm1 tiles (UNSCALED output) after.
__global__ __launch_bounds__(256, 2) void gemm1_count_kernel(
        const float* __restrict__ X, const float* __restrict__ W,
        unsigned short* __restrict__ Y, const int* __restrict__ dst,
        int* __restrict__ histg, int E, int NB, int chunk, int n) {
    __shared__ char SMEMC[smem_bytes<IN_DIM, true>()];
    if ((int)blockIdx.x < NBLK_A) {
        int* h = (int*)SMEMC;
        for (int i = threadIdx.x; i < NB; i += 256) h[i] = 0;
        __syncthreads();
        int beg = blockIdx.x * chunk;
        int end = min(E, beg + chunk);
        for (int e = beg + threadIdx.x; e < end; e += 256)
            atomicAdd(&h[dst[e] >> BSH], 1);
        __syncthreads();
        for (int i = threadIdx.x; i < NB; i += 256)
            histg[i * NBLK_A + blockIdx.x] = h[i];
        return;
    }
    mfma_gemm_body<IN_DIM, false, false, false, true>(
        SMEMC, X, W, nullptr, nullptr, Y, n, (int)blockIdx.x - NBLK_A);
}

__global__ __launch_bounds__(256, 4) void mgemm2_kernel(
        const void* X, const float* W, const float* dinv, void* Y, int n) {
    __shared__ char SMEMC[smem_bytes<HDIM, true>()];
    mfma_gemm_body<HDIM, true, true, false, true>(SMEMC, X, W, nullptr, dinv, Y, n, blockIdx.x);
}
__global__ __launch_bounds__(256, 4) void mfc_kernel(
        const float* X, const float* W, const float* bias, void* Y, int n) {
    __shared__ char SMEMC[smem_bytes<HDIM, false>()];
    mfma_gemm_body<HDIM, false, false, true, false>(SMEMC, X, W, bias, nullptr, Y, n, blockIdx.x);
}

// ---------- aggregation: CSR-vector, 8 lanes per node (R14) ----------

template<bool OBF16>
__global__ __launch_bounds__(256) void agg_kernel(
        const uint4* __restrict__ hp4, const int* __restrict__ esrc,
        const int2* __restrict__ rows, const float* __restrict__ dinv,
        const float* __restrict__ bias, void* __restrict__ out, int n) {
    const int lane = threadIdx.x & 63;
    const int j = lane & 7;
    const int step = gridDim.x * 32;
    for (int idx = blockIdx.x * 32 + (threadIdx.x >> 6) * 8 + (lane >> 3);
         idx < n; idx += step) {
        const int node = idx;
        const int2 be = rows[node];

        float acc[8];
        {   // self-loop: own row
            uint4 u = hp4[(size_t)node * 8 + j];
            acc[0] = bf2f(u.x & 0xffff); acc[1] = bf2f(u.x >> 16);
            acc[2] = bf2f(u.y & 0xffff); acc[3] = bf2f(u.y >> 16);
            acc[4] = bf2f(u.z & 0xffff); acc[5] = bf2f(u.z >> 16);
            acc[6] = bf2f(u.w & 0xffff); acc[7] = bf2f(u.w >> 16);
        }
        int k = be.x;
        for (; k + 16 <= be.y; k += 16) {       // depth-16 batches
            int s[16];
#pragma unroll
            for (int i = 0; i < 16; ++i)
                s[i] = __builtin_nontemporal_load(&esrc[k + i]);
            uint4 u[16];
#pragma unroll
            for (int i = 0; i < 16; ++i)
                u[i] = hp4[(size_t)s[i] * 8 + j];
#pragma unroll
            for (int i = 0; i < 16; ++i) {
                acc[0] += bf2f(u[i].x & 0xffff); acc[1] += bf2f(u[i].x >> 16);
                acc[2] += bf2f(u[i].y & 0xffff); acc[3] += bf2f(u[i].y >> 16);
                acc[4] += bf2f(u[i].z & 0xffff); acc[5] += bf2f(u[i].z >> 16);
                acc[6] += bf2f(u[i].w & 0xffff); acc[7] += bf2f(u[i].w >> 16);
            }
        }
        if (k < be.y) {                          // padded => exactly 8 left
            int s[8];
#pragma unroll
            for (int i = 0; i < 8; ++i)
                s[i] = __builtin_nontemporal_load(&esrc[k + i]);
            uint4 u[8];
#pragma unroll
            for (int i = 0; i < 8; ++i)
                u[i] = hp4[(size_t)s[i] * 8 + j];
#pragma unroll
            for (int i = 0; i < 8; ++i) {
                acc[0] += bf2f(u[i].x & 0xffff); acc[1] += bf2f(u[i].x >> 16);
                acc[2] += bf2f(u[i].y & 0xffff); acc[3] += bf2f(u[i].y >> 16);
                acc[4] += bf2f(u[i].z & 0xffff); acc[5] += bf2f(u[i].z >> 16);
                acc[6] += bf2f(u[i].w & 0xffff); acc[7] += bf2f(u[i].w >> 16);
            }
        }
        const float d = dinv[node];
        float o[8];
#pragma unroll
        for (int t = 0; t < 8; ++t)
            o[t] = fmaxf(fmaf(d, acc[t], bias[8 * j + t]), 0.f);

        if (OBF16) {
            uint4 pk;
            pk.x = (unsigned)f2bf_bits(o[0]) | ((unsigned)f2bf_bits(o[1]) << 16);
            pk.y = (unsigned)f2bf_bits(o[2]) | ((unsigned)f2bf_bits(o[3]) << 16);
            pk.z = (unsigned)f2bf_bits(o[4]) | ((unsigned)f2bf_bits(o[5]) << 16);
            pk.w = (unsigned)f2bf_bits(o[6]) | ((unsigned)f2bf_bits(o[7]) << 16);
            ((uint4*)out)[(size_t)node * 8 + j] = pk;
        } else {
            ((float4*)out)[(size_t)node * 16 + 2 * j]     = make_float4(o[0], o[1], o[2], o[3]);
            ((float4*)out)[(size_t)node * 16 + 2 * j + 1] = make_float4(o[4], o[5], o[6], o[7]);
        }
    }
}

extern "C" void kernel_launch(void* const* d_in, const int* in_sizes, int n_in,
                              void* d_out, int out_size, void* d_ws, size_t ws_size,
                              hipStream_t stream) {
    const float* x   = (const float*)d_in[0];
    const float* W1  = (const float*)d_in[1];
    const float* b1  = (const float*)d_in[2];
    const float* W2  = (const float*)d_in[3];
    const float* b2  = (const float*)d_in[4];
    const float* Wfc = (const float*)d_in[5];
    const float* bfc = (const float*)d_in[6];
    const int*  eidx = (const int*)d_in[7];

    const int N = in_sizes[0] / IN_DIM;     // 100000
    const int E = in_sizes[7] / 2;          // 1600000
    const int* src = eidx;
    const int* dst = eidx + E;

    const int NB    = (N + 255) >> BSH;     // 391 buckets
    const int chunk = (E + NBLK_A - 1) / NBLK_A;
    const int EP    = E + NB * PADSLK;      // padded esrc capacity

    // ws layout (ints, 16B-aligned regions). staging separate (gemm1 writes
    // hp in D1 before scatter writes staging):
    // rows[N] int2 | dinv[N] | histg[NB*256] | btot[512] | staging[E]
    //   | esrc[EP] | hp[(N+1) rows x 128B] (row N zero) | h1[N rows x 128B]
    int* p = (int*)d_ws;
    int2* rows = (int2*)p;           p += (size_t)2 * N + 2;
    float* dinv = (float*)p;         p += (size_t)((N + 3) & ~3);
    int* histg = p;                  p += (size_t)((NB * NBLK_A + 3) & ~3);
    int* btot = p;                   p += 512;
    int* staging = p;                p += (size_t)((E + 3) & ~3);
    int* esrc = p;                   p += (size_t)((EP + 3) & ~3);
    unsigned short* hp = (unsigned short*)p;   p += (size_t)(N + 1) * 32;
    unsigned short* h1 = (unsigned short*)p;   p += (size_t)N * 32;

    float* emb    = (float*)d_out;
    float* logits = emb + (size_t)N * HDIM;

    const int mB = (N + 127) / 128;         // 782 dense tiles (128 rows)
    const int aBlocks = 2048;               // 256 CU x 8 blocks, grid-stride

    // ---- D1: count || gemm1 (unscaled hp) ----
    gemm1_count_kernel<<<NBLK_A + mB, 256, 0, stream>>>(
        x, W1, hp, dst, histg, E, NB, chunk, N);

    // ---- D2-D4: CSR scan/scatter/finalize (+hp rescale) ----
    binA_scanblocks<<<NB, NBLK_A, 0, stream>>>(histg, btot);
    binA_scatter<<<NBLK_A, 256, 0, stream>>>(src, dst, histg, btot, staging, E, NB, chunk);
    binB_finalize<<<NB, 256, 0, stream>>>(staging, btot, rows, esrc, dinv,
                                          (uint4*)hp, N, NB);

    // ---- layer 1 agg ----
    agg_kernel<true><<<aBlocks, 256, 0, stream>>>(
        (const uint4*)hp, esrc, rows, dinv, b1, h1, N);

    // ---- layer 2 ----
    mgemm2_kernel<<<mB, 256, 0, stream>>>(h1, W2, dinv, hp, N);
    agg_kernel<false><<<aBlocks, 256, 0, stream>>>(
        (const uint4*)hp, esrc, rows, dinv, b2, emb, N);

    // ---- FC head ----
    mfc_kernel<<<mB, 256, 0, stream>>>(emb, Wfc, bfc, logits, N);
}